// Round 5
// baseline (240.443 us; speedup 1.0000x reference)
//
#include <hip/hip_runtime.h>
#include <math.h>

#define D 64
#define CHUNK 128   // edges per wave in k_fused; must be multiple of 32

typedef __fp16 fp16x2 __attribute__((ext_vector_type(2)));
typedef _Float16 half8 __attribute__((ext_vector_type(8)));
typedef _Float16 half4v __attribute__((ext_vector_type(4)));
typedef __attribute__((ext_vector_type(4))) float f32x4;

union h8pun { half8 v; fp16x2 h2[4]; };

// ---------------------------------------------------------------------------
// Prep: W1at/W1bt transposes, permuted fp16 W2h, segment boundaries, and
// pnode = -1 init for the boundary-partial slots.
// W2h[n][pos] = fp16(W2[pi_inv(pos)][n]),  pi_inv(pos) = (pos>>2) + 16*(pos&3).
__global__ __launch_bounds__(256) void k_prep(const float* __restrict__ W1,
                                              const float* __restrict__ W2,
                                              float* __restrict__ W1at,
                                              float* __restrict__ W1bt,
                                              _Float16* __restrict__ W2h,
                                              const int* __restrict__ seg_ids,
                                              int* __restrict__ start,
                                              int* __restrict__ pnode,
                                              int E, int N, int nslots) {
    int i = blockIdx.x * 256 + threadIdx.x;
    if (i < 3 * D * D) {
        int mat = i / (D * D), j = i % (D * D);
        if (mat == 0) {
            int r = j >> 6, c = j & 63;
            W1at[c * D + r] = W1[r * D + c];
        } else if (mat == 1) {
            int r = j >> 6, c = j & 63;
            W1bt[c * D + r] = W1[(D + r) * D + c];
        } else {
            int n = j >> 6, pos = j & 63;
            int k = (pos >> 2) + 16 * (pos & 3);   // pi_inv
            W2h[n * D + pos] = (_Float16)W2[k * D + n];
        }
    }
    if (i <= N) {
        int lo = 0, hi = E;
        while (lo < hi) {
            int mid = (lo + hi) >> 1;
            if (seg_ids[mid] < i) lo = mid + 1; else hi = mid;
        }
        start[i] = lo;
    }
    if (i < nslots) pnode[i] = -1;
}

// ---------------------------------------------------------------------------
// Combined MFMA row-projection (fp16), both passes in one launch.
// Waves [0, wavesU):     q~[r] = pi(u2e[r] @ W1a), u2e_h[r] = fp16(u2e[r])
// Waves [wavesU, ...):   p~[r] = pi(u2e[nodes[r]] @ W1b + b1)
// pi-layout store: lane writes one contiguous half4 per row (coalesced 128 B).
__global__ __launch_bounds__(256) void k_proj_both(const float* __restrict__ u2e,
                                                   const int* __restrict__ nodes,
                                                   const float* __restrict__ W1at,
                                                   const float* __restrict__ W1bt,
                                                   const float* __restrict__ b1,
                                                   _Float16* __restrict__ q,
                                                   _Float16* __restrict__ u2e_h,
                                                   _Float16* __restrict__ p,
                                                   int U, int N, int wavesU, int wavesN) {
    int lane = threadIdx.x & 63;
    int m = lane & 15, quad = lane >> 4;
    int wave = (blockIdx.x * blockDim.x + threadIdx.x) >> 6;

    const float* Wt;
    const int* idx;
    const float* bias;
    _Float16* outp;
    _Float16* copyp;
    int R, w0, wstride;
    if (wave < wavesU) {
        Wt = W1at; idx = nullptr; bias = nullptr; outp = q; copyp = u2e_h;
        R = U; w0 = wave; wstride = wavesU;
    } else {
        Wt = W1bt; idx = nodes; bias = b1; outp = p; copyp = nullptr;
        R = N; w0 = wave - wavesU; wstride = wavesN;
    }

    half8 Bf[2][4];
    float bv[4];
#pragma unroll
    for (int t = 0; t < 4; ++t) {
        int n = m + 16 * t;
        bv[t] = bias ? bias[n] : 0.0f;
#pragma unroll
        for (int kh = 0; kh < 2; ++kh) {
            const float* col = Wt + n * D + kh * 32 + quad * 8;
#pragma unroll
            for (int j = 0; j < 8; ++j) Bf[kh][t][j] = (_Float16)col[j];
        }
    }

    int ngroups = (R + 15) / 16;
    for (int g = w0; g < ngroups; g += wstride) {
        int r_ = g * 16 + m;
        int rs = r_ < R ? r_ : R - 1;
        int src = idx ? idx[rs] : rs;
        const float4* arow = (const float4*)(u2e + (size_t)src * D);
        float4 x0 = arow[quad * 2], x1 = arow[quad * 2 + 1];
        float4 y0 = arow[8 + quad * 2], y1 = arow[8 + quad * 2 + 1];
        h8pun A0, A1;
        A0.h2[0] = __builtin_amdgcn_cvt_pkrtz(x0.x, x0.y);
        A0.h2[1] = __builtin_amdgcn_cvt_pkrtz(x0.z, x0.w);
        A0.h2[2] = __builtin_amdgcn_cvt_pkrtz(x1.x, x1.y);
        A0.h2[3] = __builtin_amdgcn_cvt_pkrtz(x1.z, x1.w);
        A1.h2[0] = __builtin_amdgcn_cvt_pkrtz(y0.x, y0.y);
        A1.h2[1] = __builtin_amdgcn_cvt_pkrtz(y0.z, y0.w);
        A1.h2[2] = __builtin_amdgcn_cvt_pkrtz(y1.x, y1.y);
        A1.h2[3] = __builtin_amdgcn_cvt_pkrtz(y1.z, y1.w);
        if (copyp && r_ < R) {
            *(half8*)(copyp + (size_t)r_ * D + quad * 8) = A0.v;
            *(half8*)(copyp + (size_t)r_ * D + 32 + quad * 8) = A1.v;
        }
        f32x4 C[4];
#pragma unroll
        for (int t = 0; t < 4; ++t) C[t] = (f32x4){bv[t], bv[t], bv[t], bv[t]};
#pragma unroll
        for (int t = 0; t < 4; ++t) {
            C[t] = __builtin_amdgcn_mfma_f32_16x16x32_f16(A0.v, Bf[0][t], C[t], 0, 0, 0);
            C[t] = __builtin_amdgcn_mfma_f32_16x16x32_f16(A1.v, Bf[1][t], C[t], 0, 0, 0);
        }
        // pi-layout store: position m*4+t holds col m+16t -> one half4 per row.
#pragma unroll
        for (int r = 0; r < 4; ++r) {
            int row = g * 16 + quad * 4 + r;
            if (row < R) {
                half4v hv = {(_Float16)C[0][r], (_Float16)C[1][r],
                             (_Float16)C[2][r], (_Float16)C[3][r]};
                *(half4v*)(outp + (size_t)row * D + m * 4) = hv;
            }
        }
    }
}

// ---------------------------------------------------------------------------
// Fused edge+aggregation kernel.  One wave per CHUNK contiguous edges.
// Phase 1 (k_edge_ex shape): 32 edges/iter via fp16 MFMA; ex = exp(logit+b3)
//   and nbr stashed in per-wave LDS (no global round-trip).
// Phase 2 (k_agg_fast shape): walk the ~CHUNK/32 nodes inside the chunk;
//   weights/nbrs from LDS; 32 neighbor rows in flight.  Interior nodes
//   (all edges inside the chunk) get a final normalized direct store.
//   Boundary nodes (<=2 per wave: first crosses e_beg, last crosses e_end)
//   write (node, dsum, acc[64]) NON-atomically to their wave's partial slots;
//   k_finish stitches them.  No atomics anywhere.
__global__ __launch_bounds__(256) void k_fused(const int* __restrict__ neigh_idx,
                                               const int* __restrict__ seg_ids,
                                               const _Float16* __restrict__ q,
                                               const _Float16* __restrict__ p,
                                               const _Float16* __restrict__ u2e_h,
                                               const _Float16* __restrict__ W2h,
                                               const float* __restrict__ b2,
                                               const float* __restrict__ w3,
                                               const float* __restrict__ b3,
                                               const int* __restrict__ start,
                                               float* __restrict__ out,
                                               int* __restrict__ pnode,
                                               float* __restrict__ pdenom,
                                               float* __restrict__ pacc,
                                               int E, int nchunks) {
    __shared__ float lds_ex[4][CHUNK];
    __shared__ int lds_nb[4][CHUNK];
    int wib = (int)threadIdx.x >> 6;
    float* lex = lds_ex[wib];
    int* lnb = lds_nb[wib];

    int lane = threadIdx.x & 63;
    int m = lane & 15, quad = lane >> 4;
    int wave = (blockIdx.x * blockDim.x + threadIdx.x) >> 6;
    if (wave >= nchunks) return;
    int e_beg = wave * CHUNK;
    int e_end = e_beg + CHUNK;
    if (e_end > E) e_end = E;

    // W2 fragments (fp16, pre-permuted) + biases
    half8 Bf[2][4];
    float b2v[4], w3v[4];
#pragma unroll
    for (int t = 0; t < 4; ++t) {
        int nn = m + 16 * t;
        b2v[t] = b2[nn];
        w3v[t] = w3[nn];
        Bf[0][t] = *(const half8*)(W2h + nn * D + quad * 8);
        Bf[1][t] = *(const half8*)(W2h + nn * D + 32 + quad * 8);
    }
    float b3v = b3[0];
    const half8 hz = {0, 0, 0, 0, 0, 0, 0, 0};

    // ---- Phase 1: logits -> ex, stash ex+nbr in LDS ----
    int nit = (e_end - e_beg + 31) >> 5;
    for (int g = 0; g < nit; ++g) {
        int base = e_beg + g * 32;
        int ea = base + m, eb = ea + 16;
        int eas = ea < E ? ea : E - 1;
        int ebs = eb < E ? eb : E - 1;
        int nbra = neigh_idx[eas], sega = seg_ids[eas];
        int nbrb = neigh_idx[ebs], segb = seg_ids[ebs];
        const half8* qra = (const half8*)(q + (size_t)nbra * D);
        const half8* pra = (const half8*)(p + (size_t)sega * D);
        const half8* qrb = (const half8*)(q + (size_t)nbrb * D);
        const half8* prb = (const half8*)(p + (size_t)segb * D);
        half8 qa0 = qra[quad], qa1 = qra[quad + 4];
        half8 pa0 = pra[quad], pa1 = pra[quad + 4];
        half8 qb0 = qrb[quad], qb1 = qrb[quad + 4];
        half8 pb0 = prb[quad], pb1 = prb[quad + 4];
        half8 Aa0 = __builtin_elementwise_max(qa0 + pa0, hz);
        half8 Aa1 = __builtin_elementwise_max(qa1 + pa1, hz);
        half8 Ab0 = __builtin_elementwise_max(qb0 + pb0, hz);
        half8 Ab1 = __builtin_elementwise_max(qb1 + pb1, hz);
        f32x4 Ca[4], Cb[4];
#pragma unroll
        for (int t = 0; t < 4; ++t) {
            Ca[t] = (f32x4){b2v[t], b2v[t], b2v[t], b2v[t]};
            Cb[t] = Ca[t];
        }
#pragma unroll
        for (int t = 0; t < 4; ++t) {
            Ca[t] = __builtin_amdgcn_mfma_f32_16x16x32_f16(Aa0, Bf[0][t], Ca[t], 0, 0, 0);
            Ca[t] = __builtin_amdgcn_mfma_f32_16x16x32_f16(Aa1, Bf[1][t], Ca[t], 0, 0, 0);
            Cb[t] = __builtin_amdgcn_mfma_f32_16x16x32_f16(Ab0, Bf[0][t], Cb[t], 0, 0, 0);
            Cb[t] = __builtin_amdgcn_mfma_f32_16x16x32_f16(Ab1, Bf[1][t], Cb[t], 0, 0, 0);
        }
        float pa[4], pb[4];
#pragma unroll
        for (int r = 0; r < 4; ++r) {
            float sa = 0.0f, sb = 0.0f;
#pragma unroll
            for (int t = 0; t < 4; ++t) {
                sa += fmaxf(Ca[t][r], 0.0f) * w3v[t];
                sb += fmaxf(Cb[t][r], 0.0f) * w3v[t];
            }
            pa[r] = sa; pb[r] = sb;
        }
#pragma unroll
        for (int off = 1; off <= 8; off <<= 1) {
#pragma unroll
            for (int r = 0; r < 4; ++r) {
                pa[r] += __shfl_xor(pa[r], off, 64);
                pb[r] += __shfl_xor(pb[r], off, 64);
            }
        }
        if (m == 0) {
            int o0 = g * 32 + quad * 4;
            *(float4*)(lex + o0) = make_float4(__expf(pa[0] + b3v), __expf(pa[1] + b3v),
                                               __expf(pa[2] + b3v), __expf(pa[3] + b3v));
            *(float4*)(lex + o0 + 16) = make_float4(__expf(pb[0] + b3v), __expf(pb[1] + b3v),
                                                    __expf(pb[2] + b3v), __expf(pb[3] + b3v));
        }
        if (quad == 0) {
            lnb[g * 32 + m] = nbra;
            lnb[g * 32 + 16 + m] = nbrb;
        }
    }

    // ---- Phase 2: per-node weighted aggregation from LDS weights ----
    int n0 = seg_ids[e_beg];
    int n1 = seg_ids[e_end - 1];
    int grp = lane >> 3, sub = lane & 7;
    for (int n = n0; n <= n1; ++n) {
        int sf = start[n], tf = start[n + 1];
        int s = sf > e_beg ? sf : e_beg;
        int t = tf < e_end ? tf : e_end;
        if (s >= t) continue;
        float acc[8];
#pragma unroll
        for (int j = 0; j < 8; ++j) acc[j] = 0.0f;
        float dsum = 0.0f;
        for (int i = s; i < t; i += 32) {
#pragma unroll
            for (int uu = 0; uu < 4; ++uu) {
                int ii = i + uu * 8 + grp;
                bool v = ii < t;
                int li = (v ? ii : s) - e_beg;
                float w = lex[li];
                int nb = lnb[li];
                half8 r = *(const half8*)(u2e_h + (size_t)nb * D + sub * 8);
                if (!v) w = 0.0f;
                dsum += w;
#pragma unroll
                for (int j = 0; j < 8; ++j) acc[j] += w * (float)r[j];
            }
        }
#pragma unroll
        for (int off = 8; off <= 32; off <<= 1) {
#pragma unroll
            for (int j = 0; j < 8; ++j) acc[j] += __shfl_xor(acc[j], off, 64);
            dsum += __shfl_xor(dsum, off, 64);
        }
        bool interior = (sf >= e_beg) && (tf <= e_end);
        if (interior) {
            if (grp == 0) {
                float inv = 1.0f / dsum;
                float* o = out + (size_t)n * D + sub * 8;
                *(float4*)o = make_float4(acc[0] * inv, acc[1] * inv, acc[2] * inv, acc[3] * inv);
                *(float4*)(o + 4) = make_float4(acc[4] * inv, acc[5] * inv, acc[6] * inv, acc[7] * inv);
            }
        } else {
            int slot = wave * 2 + (sf < e_beg ? 0 : 1);
            if (grp == 0) {
                float* pa_ = pacc + (size_t)slot * D + sub * 8;
                *(float4*)pa_ = make_float4(acc[0], acc[1], acc[2], acc[3]);
                *(float4*)(pa_ + 4) = make_float4(acc[4], acc[5], acc[6], acc[7]);
            }
            if (lane == 0) {
                pdenom[slot] = dsum;
                pnode[slot] = n;
            }
        }
    }
}

// ---------------------------------------------------------------------------
// Finish: stitch boundary partials; zero-neighbor fallback.  Interior nodes
// were already written (final) by k_fused.
__global__ __launch_bounds__(256) void k_finish(const int* __restrict__ nodes,
                                                const float* __restrict__ u2e,
                                                const int* __restrict__ start,
                                                const int* __restrict__ pnode,
                                                const float* __restrict__ pdenom,
                                                const float* __restrict__ pacc,
                                                float* __restrict__ out, int N) {
    int i = blockIdx.x * 256 + threadIdx.x;
    if (i >= N * D) return;
    int n = i >> 6, d = i & 63;
    int sf = start[n], tf = start[n + 1];
    if (sf == tf) {
        out[i] = u2e[(size_t)nodes[n] * D + d];
        return;
    }
    int wlo = sf / CHUNK, whi = (tf - 1) / CHUNK;
    if (wlo == whi) return;   // interior: already final
    float acc = 0.0f, dsum = 0.0f;
    for (int w = wlo; w <= whi; ++w) {
#pragma unroll
        for (int sl = 0; sl < 2; ++sl) {
            int idx = w * 2 + sl;
            if (pnode[idx] == n) {
                acc += pacc[(size_t)idx * D + d];
                dsum += pdenom[idx];
            }
        }
    }
    out[i] = acc / dsum;
}

// ---------------------------------------------------------------------------
extern "C" void kernel_launch(void* const* d_in, const int* in_sizes, int n_in,
                              void* d_out, int out_size, void* d_ws, size_t ws_size,
                              hipStream_t stream) {
    const int* nodes = (const int*)d_in[0];
    const int* neigh_idx = (const int*)d_in[1];
    const int* seg_ids = (const int*)d_in[2];
    const float* u2e = (const float*)d_in[3];
    const float* W1 = (const float*)d_in[4];
    const float* b1 = (const float*)d_in[5];
    const float* W2 = (const float*)d_in[6];
    const float* b2 = (const float*)d_in[7];
    const float* w3 = (const float*)d_in[8];
    const float* b3 = (const float*)d_in[9];
    float* out = (float*)d_out;

    int N = in_sizes[0];
    int E = in_sizes[1];
    int U = in_sizes[3] / D;

    int nchunks = (E + CHUNK - 1) / CHUNK;
    int nslots = nchunks * 2;

    char* ws = (char*)d_ws;
    size_t off = 0;
    auto alloc = [&](size_t bytes) {
        void* ptr = ws + off;
        off = (off + bytes + 255) & ~(size_t)255;
        return ptr;
    };
    int* start = (int*)alloc((size_t)(N + 1) * 4);
    float* W1at = (float*)alloc((size_t)D * D * 4);
    float* W1bt = (float*)alloc((size_t)D * D * 4);
    _Float16* W2h = (_Float16*)alloc((size_t)D * D * 2);
    _Float16* q = (_Float16*)alloc((size_t)U * D * 2);
    _Float16* p = (_Float16*)alloc((size_t)N * D * 2);
    _Float16* u2e_h = (_Float16*)alloc((size_t)U * D * 2);
    int* pnode = (int*)alloc((size_t)nslots * 4);
    float* pdenom = (float*)alloc((size_t)nslots * 4);
    float* pacc = (float*)alloc((size_t)nslots * D * 4);
    (void)ws_size;

    int prep_n = (N + 1) > 3 * D * D ? (N + 1) : 3 * D * D;
    if (prep_n < nslots) prep_n = nslots;
    k_prep<<<(prep_n + 255) / 256, 256, 0, stream>>>(W1, W2, W1at, W1bt, W2h,
                                                     seg_ids, start, pnode, E, N, nslots);
    const int wavesU = 6144, wavesN = 2048;
    k_proj_both<<<(wavesU + wavesN) / 4, 256, 0, stream>>>(u2e, nodes, W1at, W1bt, b1,
                                                           q, u2e_h, p, U, N, wavesU, wavesN);
    k_fused<<<(nchunks + 3) / 4, 256, 0, stream>>>(neigh_idx, seg_ids, q, p, u2e_h,
                                                   W2h, b2, w3, b3, start, out,
                                                   pnode, pdenom, pacc, E, nchunks);
    k_finish<<<(N * D + 255) / 256, 256, 0, stream>>>(nodes, u2e, start, pnode,
                                                      pdenom, pacc, out, N);
}

// Round 6
// 208.751 us; speedup vs baseline: 1.1518x; 1.1518x over previous
//
#include <hip/hip_runtime.h>
#include <math.h>

#define D 64

typedef __fp16 fp16x2 __attribute__((ext_vector_type(2)));
typedef _Float16 half8 __attribute__((ext_vector_type(8)));
typedef _Float16 half4v __attribute__((ext_vector_type(4)));
typedef __attribute__((ext_vector_type(4))) float f32x4;

union h8pun { half8 v; fp16x2 h2[4]; };

// ---------------------------------------------------------------------------
// Combined MFMA row-projection (fp16), both passes in one launch, PLUS the
// former k_prep roles folded in as predicated thread-work:
//   - tid <= N:                start[tid] via binary search on sorted seg_ids
//   - tid in (N, N+D*D]:       W2h[n][pos] = fp16(W2[pi_inv(pos)][n])
// W1at/W1bt staging is gone: each wave transposes W1 on the fly (W1 is 32 KB,
// L1/L2-resident; 64 strided scalar loads per wave is noise vs streaming).
// Waves [0, wavesU):     q~[r] = pi(u2e[r] @ W1a), u2e_h[r] = fp16(u2e[r])
// Waves [wavesU, ...):   p~[r] = pi(u2e[nodes[r]] @ W1b + b1)
// pi-layout store: lane writes one contiguous half4 per row (coalesced 128 B).
__global__ __launch_bounds__(256) void k_proj_both(const float* __restrict__ u2e,
                                                   const int* __restrict__ nodes,
                                                   const float* __restrict__ W1,
                                                   const float* __restrict__ b1,
                                                   const float* __restrict__ W2,
                                                   _Float16* __restrict__ W2h,
                                                   const int* __restrict__ seg_ids,
                                                   int* __restrict__ start,
                                                   _Float16* __restrict__ q,
                                                   _Float16* __restrict__ u2e_h,
                                                   _Float16* __restrict__ p,
                                                   int U, int N, int E,
                                                   int wavesU, int wavesN) {
    // ---- folded prep roles ----
    int tid = blockIdx.x * blockDim.x + (int)threadIdx.x;
    if (tid <= N) {
        int lo = 0, hi = E;
        while (lo < hi) {
            int mid = (lo + hi) >> 1;
            if (seg_ids[mid] < tid) lo = mid + 1; else hi = mid;
        }
        start[tid] = lo;
    } else if (tid <= N + D * D) {
        int j = tid - (N + 1);
        int n = j >> 6, pos = j & 63;
        int k = (pos >> 2) + 16 * (pos & 3);   // pi_inv
        W2h[n * D + pos] = (_Float16)W2[k * D + n];
    }

    int lane = threadIdx.x & 63;
    int m = lane & 15, quad = lane >> 4;
    int wave = (blockIdx.x * blockDim.x + threadIdx.x) >> 6;

    const int* idx;
    const float* bias;
    _Float16* outp;
    _Float16* copyp;
    int R, w0, wstride, w1off;
    if (wave < wavesU) {
        idx = nullptr; bias = nullptr; outp = q; copyp = u2e_h;
        R = U; w0 = wave; wstride = wavesU; w1off = 0;
    } else {
        idx = nodes; bias = b1; outp = p; copyp = nullptr;
        R = N; w0 = wave - wavesU; wstride = wavesN; w1off = D;
    }

    // on-the-fly transpose: Bf[kh][t][j] = W1[(w1off + kh*32+quad*8+j)*D + n]
    half8 Bf[2][4];
    float bv[4];
#pragma unroll
    for (int t = 0; t < 4; ++t) {
        int n = m + 16 * t;
        bv[t] = bias ? bias[n] : 0.0f;
#pragma unroll
        for (int kh = 0; kh < 2; ++kh) {
            int k0 = w1off + kh * 32 + quad * 8;
#pragma unroll
            for (int j = 0; j < 8; ++j) Bf[kh][t][j] = (_Float16)W1[(size_t)(k0 + j) * D + n];
        }
    }

    int ngroups = (R + 15) / 16;
    for (int g = w0; g < ngroups; g += wstride) {
        int r_ = g * 16 + m;
        int rs = r_ < R ? r_ : R - 1;
        int src = idx ? idx[rs] : rs;
        const float4* arow = (const float4*)(u2e + (size_t)src * D);
        float4 x0 = arow[quad * 2], x1 = arow[quad * 2 + 1];
        float4 y0 = arow[8 + quad * 2], y1 = arow[8 + quad * 2 + 1];
        h8pun A0, A1;
        A0.h2[0] = __builtin_amdgcn_cvt_pkrtz(x0.x, x0.y);
        A0.h2[1] = __builtin_amdgcn_cvt_pkrtz(x0.z, x0.w);
        A0.h2[2] = __builtin_amdgcn_cvt_pkrtz(x1.x, x1.y);
        A0.h2[3] = __builtin_amdgcn_cvt_pkrtz(x1.z, x1.w);
        A1.h2[0] = __builtin_amdgcn_cvt_pkrtz(y0.x, y0.y);
        A1.h2[1] = __builtin_amdgcn_cvt_pkrtz(y0.z, y0.w);
        A1.h2[2] = __builtin_amdgcn_cvt_pkrtz(y1.x, y1.y);
        A1.h2[3] = __builtin_amdgcn_cvt_pkrtz(y1.z, y1.w);
        if (copyp && r_ < R) {
            *(half8*)(copyp + (size_t)r_ * D + quad * 8) = A0.v;
            *(half8*)(copyp + (size_t)r_ * D + 32 + quad * 8) = A1.v;
        }
        f32x4 C[4];
#pragma unroll
        for (int t = 0; t < 4; ++t) C[t] = (f32x4){bv[t], bv[t], bv[t], bv[t]};
#pragma unroll
        for (int t = 0; t < 4; ++t) {
            C[t] = __builtin_amdgcn_mfma_f32_16x16x32_f16(A0.v, Bf[0][t], C[t], 0, 0, 0);
            C[t] = __builtin_amdgcn_mfma_f32_16x16x32_f16(A1.v, Bf[1][t], C[t], 0, 0, 0);
        }
        // pi-layout store: position m*4+t holds col m+16t -> one half4 per row.
#pragma unroll
        for (int r = 0; r < 4; ++r) {
            int row = g * 16 + quad * 4 + r;
            if (row < R) {
                half4v hv = {(_Float16)C[0][r], (_Float16)C[1][r],
                             (_Float16)C[2][r], (_Float16)C[3][r]};
                *(half4v*)(outp + (size_t)row * D + m * 4) = hv;
            }
        }
    }
}

// ---------------------------------------------------------------------------
// Edge kernel: logits via fp16 MFMA, 32 edges per wave-iteration (two 16-edge
// A-sets share B-frags), storing ex = exp(logit + b3).  Softmax is
// shift-invariant and logits are O(1), so no max subtraction (validated).
// NEW: neigh/seg indices for the NEXT grid-stride iteration are prefetched one
// iteration ahead, removing the idx-load -> row-gather serial dependency from
// the per-iteration critical chain.
__global__ __launch_bounds__(256) void k_edge_ex(const int* __restrict__ neigh_idx,
                                                 const int* __restrict__ seg_ids,
                                                 const _Float16* __restrict__ q,
                                                 const _Float16* __restrict__ p,
                                                 const _Float16* __restrict__ W2h,
                                                 const float* __restrict__ b2,
                                                 const float* __restrict__ w3,
                                                 const float* __restrict__ b3,
                                                 float* __restrict__ exb, int E) {
    int lane = threadIdx.x & 63;
    int m = lane & 15, quad = lane >> 4;

    half8 Bf[2][4];
    float b2v[4], w3v[4];
#pragma unroll
    for (int t = 0; t < 4; ++t) {
        int n = m + 16 * t;
        b2v[t] = b2[n];
        w3v[t] = w3[n];
        Bf[0][t] = *(const half8*)(W2h + n * D + quad * 8);
        Bf[1][t] = *(const half8*)(W2h + n * D + 32 + quad * 8);
    }
    float b3v = b3[0];
    const half8 hz = {0, 0, 0, 0, 0, 0, 0, 0};

    int ngroups = (E + 31) / 32;
    int wave = (blockIdx.x * blockDim.x + threadIdx.x) >> 6;
    int nwaves = (gridDim.x * blockDim.x) >> 6;

    // prefetch first iteration's indices
    int nbra = 0, sega = 0, nbrb = 0, segb = 0;
    if (wave < ngroups) {
        int ea = wave * 32 + m, eb = ea + 16;
        int eas = ea < E ? ea : E - 1;
        int ebs = eb < E ? eb : E - 1;
        nbra = neigh_idx[eas]; sega = seg_ids[eas];
        nbrb = neigh_idx[ebs]; segb = seg_ids[ebs];
    }
    for (int g = wave; g < ngroups; g += nwaves) {
        // issue next iteration's idx loads early (independent of this iter)
        int gn = g + nwaves;
        int nbra_n = 0, sega_n = 0, nbrb_n = 0, segb_n = 0;
        if (gn < ngroups) {
            int ea = gn * 32 + m, eb = ea + 16;
            int eas = ea < E ? ea : E - 1;
            int ebs = eb < E ? eb : E - 1;
            nbra_n = neigh_idx[eas]; sega_n = seg_ids[eas];
            nbrb_n = neigh_idx[ebs]; segb_n = seg_ids[ebs];
        }
        // row gathers for the current iteration (idx already resident)
        const half8* qra = (const half8*)(q + (size_t)nbra * D);
        const half8* pra = (const half8*)(p + (size_t)sega * D);
        const half8* qrb = (const half8*)(q + (size_t)nbrb * D);
        const half8* prb = (const half8*)(p + (size_t)segb * D);
        half8 qa0 = qra[quad], qa1 = qra[quad + 4];
        half8 pa0 = pra[quad], pa1 = pra[quad + 4];
        half8 qb0 = qrb[quad], qb1 = qrb[quad + 4];
        half8 pb0 = prb[quad], pb1 = prb[quad + 4];
        half8 Aa0 = __builtin_elementwise_max(qa0 + pa0, hz);
        half8 Aa1 = __builtin_elementwise_max(qa1 + pa1, hz);
        half8 Ab0 = __builtin_elementwise_max(qb0 + pb0, hz);
        half8 Ab1 = __builtin_elementwise_max(qb1 + pb1, hz);
        f32x4 Ca[4], Cb[4];
#pragma unroll
        for (int t = 0; t < 4; ++t) {
            Ca[t] = (f32x4){b2v[t], b2v[t], b2v[t], b2v[t]};
            Cb[t] = Ca[t];
        }
#pragma unroll
        for (int t = 0; t < 4; ++t) {
            Ca[t] = __builtin_amdgcn_mfma_f32_16x16x32_f16(Aa0, Bf[0][t], Ca[t], 0, 0, 0);
            Ca[t] = __builtin_amdgcn_mfma_f32_16x16x32_f16(Aa1, Bf[1][t], Ca[t], 0, 0, 0);
            Cb[t] = __builtin_amdgcn_mfma_f32_16x16x32_f16(Ab0, Bf[0][t], Cb[t], 0, 0, 0);
            Cb[t] = __builtin_amdgcn_mfma_f32_16x16x32_f16(Ab1, Bf[1][t], Cb[t], 0, 0, 0);
        }
        float pa[4], pb[4];
#pragma unroll
        for (int r = 0; r < 4; ++r) {
            float sa = 0.0f, sb = 0.0f;
#pragma unroll
            for (int t = 0; t < 4; ++t) {
                sa += fmaxf(Ca[t][r], 0.0f) * w3v[t];
                sb += fmaxf(Cb[t][r], 0.0f) * w3v[t];
            }
            pa[r] = sa; pb[r] = sb;
        }
#pragma unroll
        for (int off = 1; off <= 8; off <<= 1) {
#pragma unroll
            for (int r = 0; r < 4; ++r) {
                pa[r] += __shfl_xor(pa[r], off, 64);
                pb[r] += __shfl_xor(pb[r], off, 64);
            }
        }
        // ex = exp(logit + b3); store 4+4 contiguous edges from each quad's m==0 lane
        if (m == 0) {
            int e0 = g * 32 + quad * 4;
            if (e0 + 3 < E)
                *(float4*)(exb + e0) = make_float4(__expf(pa[0] + b3v), __expf(pa[1] + b3v),
                                                   __expf(pa[2] + b3v), __expf(pa[3] + b3v));
            else
#pragma unroll
                for (int r = 0; r < 4; ++r)
                    if (e0 + r < E) exb[e0 + r] = __expf(pa[r] + b3v);
            int e1 = e0 + 16;
            if (e1 + 3 < E)
                *(float4*)(exb + e1) = make_float4(__expf(pb[0] + b3v), __expf(pb[1] + b3v),
                                                   __expf(pb[2] + b3v), __expf(pb[3] + b3v));
            else
#pragma unroll
                for (int r = 0; r < 4; ++r)
                    if (e1 + r < E) exb[e1 + r] = __expf(pb[r] + b3v);
        }
        // rotate prefetched indices
        nbra = nbra_n; sega = sega_n; nbrb = nbrb_n; segb = segb_n;
    }
}

// ---------------------------------------------------------------------------
// Wave per node: single gather-accumulate pass.  The softmax denominator is
// accumulated IN-REGISTER alongside acc[] (dsum += w), reduced by the same
// butterfly, and applied as 1/dsum at the store -- no extra pass, no atomics.
// 8 lane-groups x 4-deep unroll = 32 neighbor rows in flight per wave.
__global__ __launch_bounds__(256) void k_agg_fast(const int* __restrict__ nodes,
                                                  const int* __restrict__ neigh_idx,
                                                  const float* __restrict__ u2e,
                                                  const _Float16* __restrict__ u2e_h,
                                                  const float* __restrict__ exb,
                                                  const int* __restrict__ start,
                                                  float* __restrict__ out, int N) {
    int n = blockIdx.x * 4 + ((int)threadIdx.x >> 6);
    int lane = threadIdx.x & 63;
    if (n >= N) return;
    int s = start[n];
    int t = start[n + 1];
    if (s == t) {  // no neighbors: own embedding (fp32, exact)
        int node = nodes[n];
        out[(size_t)n * D + lane] = u2e[(size_t)node * D + lane];
        return;
    }

    int grp = lane >> 3, sub = lane & 7;   // 8 groups of 8 lanes
    float acc[8];
#pragma unroll
    for (int j = 0; j < 8; ++j) acc[j] = 0.0f;
    float dsum = 0.0f;
    for (int i = s; i < t; i += 32) {
#pragma unroll
        for (int uu = 0; uu < 4; ++uu) {
            int ii = i + uu * 8 + grp;
            bool v = ii < t;
            int is = v ? ii : s;
            float w = exb[is];
            int nb = neigh_idx[is];
            half8 r = *(const half8*)(u2e_h + (size_t)nb * D + sub * 8);
            if (!v) w = 0.0f;
            dsum += w;
#pragma unroll
            for (int j = 0; j < 8; ++j) acc[j] += w * (float)r[j];
        }
    }
#pragma unroll
    for (int off = 8; off <= 32; off <<= 1) {
#pragma unroll
        for (int j = 0; j < 8; ++j) acc[j] += __shfl_xor(acc[j], off, 64);
        dsum += __shfl_xor(dsum, off, 64);
    }
    if (grp == 0) {
        float inv = 1.0f / dsum;
        float* o = out + (size_t)n * D + sub * 8;
        *(float4*)o = make_float4(acc[0] * inv, acc[1] * inv, acc[2] * inv, acc[3] * inv);
        *(float4*)(o + 4) = make_float4(acc[4] * inv, acc[5] * inv, acc[6] * inv, acc[7] * inv);
    }
}

// ---------------------------------------------------------------------------
extern "C" void kernel_launch(void* const* d_in, const int* in_sizes, int n_in,
                              void* d_out, int out_size, void* d_ws, size_t ws_size,
                              hipStream_t stream) {
    const int* nodes = (const int*)d_in[0];
    const int* neigh_idx = (const int*)d_in[1];
    const int* seg_ids = (const int*)d_in[2];
    const float* u2e = (const float*)d_in[3];
    const float* W1 = (const float*)d_in[4];
    const float* b1 = (const float*)d_in[5];
    const float* W2 = (const float*)d_in[6];
    const float* b2 = (const float*)d_in[7];
    const float* w3 = (const float*)d_in[8];
    const float* b3 = (const float*)d_in[9];
    float* out = (float*)d_out;

    int N = in_sizes[0];
    int E = in_sizes[1];
    int U = in_sizes[3] / D;

    char* ws = (char*)d_ws;
    size_t off = 0;
    auto alloc = [&](size_t bytes) {
        void* ptr = ws + off;
        off = (off + bytes + 255) & ~(size_t)255;
        return ptr;
    };
    float* exb = (float*)alloc((size_t)E * 4);
    int* start = (int*)alloc((size_t)(N + 1) * 4);
    _Float16* W2h = (_Float16*)alloc((size_t)D * D * 2);
    _Float16* q = (_Float16*)alloc((size_t)U * D * 2);
    _Float16* p = (_Float16*)alloc((size_t)N * D * 2);
    _Float16* u2e_h = (_Float16*)alloc((size_t)U * D * 2);
    (void)ws_size;

    const int wavesU = 6144, wavesN = 2048;
    k_proj_both<<<(wavesU + wavesN) / 4, 256, 0, stream>>>(u2e, nodes, W1, b1, W2, W2h,
                                                           seg_ids, start, q, u2e_h, p,
                                                           U, N, E, wavesU, wavesN);
    k_edge_ex<<<2048, 256, 0, stream>>>(neigh_idx, seg_ids, q, p, W2h,
                                        b2, w3, b3, exb, E);
    k_agg_fast<<<(N + 3) / 4, 256, 0, stream>>>(nodes, neigh_idx, u2e, u2e_h,
                                                exb, start, out, N);
}